// Round 6
// baseline (444.668 us; speedup 1.0000x reference)
//
#include <hip/hip_runtime.h>
#include <math.h>

#define BB 16
#define SS 2048
#define DD 768
#define NROW (BB * SS) // 32768
#define NSLICE 16      // o-dimension split for weight fold

typedef float nfloat4 __attribute__((ext_vector_type(4))); // native vec for nontemporal builtins

// ws layout (float-granular offsets)
#define PART_OFF  0                        // NSLICE*2304 floats: partial w3 sums
#define W3_OFF    (PART_OFF + NSLICE*2304) // 2304 floats: w3[k][i]
#define BIAS_OFF  (W3_OFF + 2304)          // 1 float (+pad)
#define CNT_OFF   (BIAS_OFF + 64)          // BB ints: per-batch completion counters
#define E0_OFF    (CNT_OFF + 64)           // NROW floats each
#define E1_OFF    (E0_OFF + NROW)
#define E2_OFF    (E1_OFF + NROW)
#define WPK_OFF   (E2_OFF + NROW)          // 2*NROW floats: (wcur, wnext) pairs
#define FT_OFF    (WPK_OFF + 2*NROW)       // NROW ints: fire time of output row j
#define LEN_OFF   (FT_OFF + NROW)          // BB ints

// K1a: partial fold over an o-slice. grid = NSLICE*9 blocks.
// Also zeroes the per-batch completion counters (used 2 kernels later).
__global__ __launch_bounds__(256) void k1a_fold_part(
    const float* __restrict__ conv_w, const float* __restrict__ lin_w,
    float* __restrict__ ws) {
  int tid = threadIdx.x;
  if (blockIdx.x == 0 && tid < BB) ((int*)ws)[CNT_OFF + tid] = 0;
  int slice = blockIdx.x / 9, cb = blockIdx.x % 9;
  int c = cb * 256 + tid; // c in [0,2304)
  int o0 = slice * (DD / NSLICE);
  float acc = 0.f;
#pragma unroll 4
  for (int oo = 0; oo < DD / NSLICE; ++oo) {
    int o = o0 + oo;
    acc = fmaf(lin_w[o], conv_w[(size_t)o * 2304 + c], acc); // coalesced over c
  }
  ws[PART_OFF + slice * 2304 + c] = acc;
}

// K1r: reduce partials -> w3[k*DD+i]; block 9 computes bias_eff.
__global__ __launch_bounds__(256) void k1r_fold_reduce(
    const float* __restrict__ conv_b, const float* __restrict__ lin_w,
    const float* __restrict__ lin_b, float* __restrict__ ws) {
  __shared__ float red[256];
  int tid = threadIdx.x;
  if (blockIdx.x < 9) {
    int c = blockIdx.x * 256 + tid;
    float acc = 0.f;
#pragma unroll
    for (int s = 0; s < NSLICE; ++s) acc += ws[PART_OFF + s * 2304 + c];
    int i = c / 3, k = c % 3;
    ws[W3_OFF + k * DD + i] = acc;
  } else {
    float p = 0.f;
    for (int o = tid; o < DD; o += 256) p = fmaf(lin_w[o], conv_b[o], p);
    red[tid] = p;
    __syncthreads();
    for (int off = 128; off > 0; off >>= 1) {
      if (tid < off) red[tid] += red[tid + off];
      __syncthreads();
    }
    if (tid == 0) ws[BIAS_OFF] = red[0] + lin_b[0];
  }
}

// K2: dots for rows s <= len[b] (one wave per row, 4 rows/block, 512 blocks/batch),
// then the LAST completing block of each batch runs the fused alpha+prefix-scan
// for that batch (decoupled-lookback-style release/acquire on cnt[b]).
__global__ __launch_bounds__(256) void k2_dots_scan(
    const float* __restrict__ x, const int* __restrict__ lens,
    float* __restrict__ ws, float* __restrict__ out) {
  __shared__ float w3[2304];
  __shared__ double wtot[4];
  __shared__ int oldc;
  const int tid = threadIdx.x, wave = tid >> 6, lane = tid & 63;
  const int blk = blockIdx.x;
  const int b = blk >> 9;          // 512 blocks per batch
  const int len = lens[b];
  const int baseS = (blk & 511) * 4;

  if (baseS <= len) {              // block-uniform: all 4 rows share b
    for (int c = tid; c < 2304; c += 256) w3[c] = ws[W3_OFF + c];
    __syncthreads();
    const int s = baseS + wave;
    if (s <= len) {                // e needed up to index len (stencil)
      const int row = b * SS + s;
      const float4* xr = (const float4*)(x + (size_t)row * DD);
      const float4* w0p = (const float4*)(w3);
      const float4* w1p = (const float4*)(w3 + DD);
      const float4* w2p = (const float4*)(w3 + 2 * DD);
      float a0 = 0.f, a1 = 0.f, a2 = 0.f;
#pragma unroll
      for (int q = 0; q < 3; ++q) {
        int f = lane + q * 64;     // float4 index, 192 per row
        float4 xv = xr[f];
        float4 w0 = w0p[f], w1 = w1p[f], w2 = w2p[f];
        a0 += w0.x * xv.x + w0.y * xv.y + w0.z * xv.z + w0.w * xv.w;
        a1 += w1.x * xv.x + w1.y * xv.y + w1.z * xv.z + w1.w * xv.w;
        a2 += w2.x * xv.x + w2.y * xv.y + w2.z * xv.z + w2.w * xv.w;
      }
#pragma unroll
      for (int m = 1; m < 64; m <<= 1) {
        a0 += __shfl_xor(a0, m);
        a1 += __shfl_xor(a1, m);
        a2 += __shfl_xor(a2, m);
      }
      if (lane == 0) {
        ws[E0_OFF + row] = a0;
        ws[E1_OFF + row] = a1;
        ws[E2_OFF + row] = a2;
      }
    }
  }
  // completion protocol: release our e-writes, detect last block of batch
  __syncthreads();
  if (tid == 0)
    oldc = __hip_atomic_fetch_add(((int*)ws) + CNT_OFF + b, 1,
                                  __ATOMIC_RELEASE, __HIP_MEMORY_SCOPE_AGENT);
  __syncthreads();
  if (oldc != 511) return;
  if (tid == 0)  // acquire: invalidate local caches so cross-XCD e-writes are visible
    (void)__hip_atomic_load(((int*)ws) + CNT_OFF + b,
                            __ATOMIC_ACQUIRE, __HIP_MEMORY_SCOPE_AGENT);
  __syncthreads();

  // ---- fused alpha (stencil+sigmoid+mask) + per-batch prefix scan ----
  const float* e0 = ws + E0_OFF + b * SS;
  const float* e1 = ws + E1_OFF + b * SS;
  const float* e2 = ws + E2_OFF + b * SS;
  float2* wpk = (float2*)(ws + WPK_OFF) + b * SS;
  int* ft = ((int*)ws) + FT_OFF + b * SS;
  const float bias = ws[BIAS_OFF];
  const int t0 = tid * 8;
  float a[8];
  double incl[8];
  double run = 0.0;
#pragma unroll
  for (int e = 0; e < 8; ++e) {
    int t = t0 + e;
    float av = 0.f;
    if (t < len) {
      float z = bias + e1[t];
      if (t > 0) z += e0[t - 1];
      if (t < SS - 1) z += e2[t + 1]; // SAME-pad: no contribution at t = S-1
      av = 1.f / (1.f + expf(-z));
    }
    a[e] = av;
    run += (double)av;
    incl[e] = run;
  }
  double v = run; // inclusive wave-scan of per-thread totals
#pragma unroll
  for (int m = 1; m < 64; m <<= 1) {
    double o = __shfl_up(v, m);
    if (lane >= m) v += o;
  }
  if (lane == 63) wtot[wave] = v;
  __syncthreads();
  double woff = 0.0;
  for (int w = 0; w < wave; ++w) woff += wtot[w];
  double excl = woff + v - run;
  double Pprev = excl;
  int Fprev = (int)floor(excl);
#pragma unroll
  for (int e = 0; e < 8; ++e) {
    int t = t0 + e;
    double P = excl + incl[e];
    int F = (int)floor(P);
    bool fire = (F > Fprev); // alpha in [0,1) => F steps by at most 1
    float2 wv;
    wv.x = fire ? (float)((double)F - Pprev) : a[e]; // a1 on fire, alpha otherwise
    wv.y = fire ? (float)(P - (double)F) : 0.f;      // a2 carried to next segment
    wpk[t] = wv;
    if (fire) ft[F - 1] = t;
    Pprev = P;
    Fprev = F;
  }
  if (tid == 255) {
    int L = (int)floor(woff + v);
    ((int*)ws)[LEN_OFF + b] = L;
    out[(size_t)NROW * DD + b] = (float)L;
  }
}

// K4: one wave per output row j. Row j = wnext[ft[j-1]]*x[ft[j-1]]
//   + sum_{ft[j-1] < t < ft[j]} wcur[t]*x[t] + wcur[ft[j]]*x[ft[j]]. j>=L -> zeros.
// Nontemporal stores (native vec type): out is write-once, keep L2 for the x gather.
__global__ __launch_bounds__(256) void k4_emit(
    const float* __restrict__ x, const float* __restrict__ ws_ro,
    float* __restrict__ out) {
  int tid = threadIdx.x, wave = tid >> 6, lane = tid & 63;
  int row = blockIdx.x * 4 + wave; // b*SS + j
  int b = row >> 11, j = row & (SS - 1);
  nfloat4* orow = (nfloat4*)(out + (size_t)row * DD);
  int L = ((const int*)ws_ro)[LEN_OFF + b];
  if (j >= L) {
    nfloat4 z = {0.f, 0.f, 0.f, 0.f};
    __builtin_nontemporal_store(z, orow + lane);
    __builtin_nontemporal_store(z, orow + lane + 64);
    __builtin_nontemporal_store(z, orow + lane + 128);
    return;
  }
  const int* ft = ((const int*)ws_ro) + FT_OFF + b * SS;
  const float2* wpk = (const float2*)(ws_ro + WPK_OFF) + b * SS;
  int start = (j == 0) ? 0 : ft[j - 1];
  int end = ft[j];
  nfloat4 acc0 = {0, 0, 0, 0}, acc1 = {0, 0, 0, 0}, acc2 = {0, 0, 0, 0};
  for (int t = start; t <= end; ++t) {
    float2 wv = wpk[t];
    float w = (j > 0 && t == start) ? wv.y : wv.x;
    const nfloat4* xr = (const nfloat4*)(x + ((size_t)b * SS + t) * DD);
    nfloat4 v0 = xr[lane], v1 = xr[lane + 64], v2 = xr[lane + 128];
    acc0 += w * v0;
    acc1 += w * v1;
    acc2 += w * v2;
  }
  __builtin_nontemporal_store(acc0, orow + lane);
  __builtin_nontemporal_store(acc1, orow + lane + 64);
  __builtin_nontemporal_store(acc2, orow + lane + 128);
}

extern "C" void kernel_launch(void* const* d_in, const int* in_sizes, int n_in,
                              void* d_out, int out_size, void* d_ws, size_t ws_size,
                              hipStream_t stream) {
  const float* x      = (const float*)d_in[0]; // (B,S,D)
  const int*   lens   = (const int*)d_in[1];   // (B,)
  const float* conv_w = (const float*)d_in[2]; // (D,D,3)
  const float* conv_b = (const float*)d_in[3]; // (D,)
  const float* lin_w  = (const float*)d_in[4]; // (1,D)
  const float* lin_b  = (const float*)d_in[5]; // (1,)
  float* out = (float*)d_out;                  // B*S*D floats then B lens (as float)
  float* ws = (float*)d_ws;

  k1a_fold_part<<<NSLICE * 9, 256, 0, stream>>>(conv_w, lin_w, ws);
  k1r_fold_reduce<<<10, 256, 0, stream>>>(conv_b, lin_w, lin_b, ws);
  k2_dots_scan<<<NROW / 4, 256, 0, stream>>>(x, lens, ws, out);
  k4_emit<<<NROW / 4, 256, 0, stream>>>(x, ws, out);
}

// Round 7
// 198.970 us; speedup vs baseline: 2.2349x; 2.2349x over previous
//
#include <hip/hip_runtime.h>
#include <math.h>

#define BB 16
#define SS 2048
#define DD 768
#define NROW (BB * SS) // 32768
#define NSLICE 16      // o-dimension split for weight fold

typedef float nfloat4 __attribute__((ext_vector_type(4))); // native vec for nontemporal builtins

// ws layout (float-granular offsets)
#define PART_OFF  0                        // NSLICE*2304 floats: partial w3 sums
#define W3_OFF    (PART_OFF + NSLICE*2304) // 2304 floats: w3[k][i]
#define BIAS_OFF  (W3_OFF + 2304)          // 1 float (+pad)
#define E0_OFF    (BIAS_OFF + 64)          // NROW floats each
#define E1_OFF    (E0_OFF + NROW)
#define E2_OFF    (E1_OFF + NROW)
#define WPK_OFF   (E2_OFF + NROW)          // 2*NROW floats: (wcur, wnext) pairs
#define FT_OFF    (WPK_OFF + 2*NROW)       // NROW ints: fire time of output row j
#define LEN_OFF   (FT_OFF + NROW)          // BB ints

// K1a: partial fold over an o-slice. grid = NSLICE*9 blocks.
__global__ __launch_bounds__(256) void k1a_fold_part(
    const float* __restrict__ conv_w, const float* __restrict__ lin_w,
    float* __restrict__ ws) {
  int tid = threadIdx.x;
  int slice = blockIdx.x / 9, cb = blockIdx.x % 9;
  int c = cb * 256 + tid; // c in [0,2304)
  int o0 = slice * (DD / NSLICE);
  float acc = 0.f;
#pragma unroll 4
  for (int oo = 0; oo < DD / NSLICE; ++oo) {
    int o = o0 + oo;
    acc = fmaf(lin_w[o], conv_w[(size_t)o * 2304 + c], acc); // coalesced over c
  }
  ws[PART_OFF + slice * 2304 + c] = acc;
}

// K1r: reduce partials -> w3[k*DD+i]; block 9 computes bias_eff.
__global__ __launch_bounds__(256) void k1r_fold_reduce(
    const float* __restrict__ conv_b, const float* __restrict__ lin_w,
    const float* __restrict__ lin_b, float* __restrict__ ws) {
  __shared__ float red[256];
  int tid = threadIdx.x;
  if (blockIdx.x < 9) {
    int c = blockIdx.x * 256 + tid;
    float acc = 0.f;
#pragma unroll
    for (int s = 0; s < NSLICE; ++s) acc += ws[PART_OFF + s * 2304 + c];
    int i = c / 3, k = c % 3;
    ws[W3_OFF + k * DD + i] = acc;
  } else {
    float p = 0.f;
    for (int o = tid; o < DD; o += 256) p = fmaf(lin_w[o], conv_b[o], p);
    red[tid] = p;
    __syncthreads();
    for (int off = 128; off > 0; off >>= 1) {
      if (tid < off) red[tid] += red[tid + off];
      __syncthreads();
    }
    if (tid == 0) ws[BIAS_OFF] = red[0] + lin_b[0];
  }
}

// K2a: per encoder row s <= len[b], e_k[row] = sum_i w3[k][i]*x[row][i].
// One wave per row, 4 rows/block (block-uniform batch); whole-block skip when
// all 4 rows are past len (saves the 9 KB w3 LDS fill too).
__global__ __launch_bounds__(256) void k2a_dots(
    const float* __restrict__ x, const float* __restrict__ ws,
    const int* __restrict__ lens,
    float* __restrict__ e0, float* __restrict__ e1, float* __restrict__ e2) {
  __shared__ float w3[2304];
  const int tid = threadIdx.x, wave = tid >> 6, lane = tid & 63;
  const int blk = blockIdx.x;
  const int b = blk >> 9;          // 512 blocks per batch
  const int len = lens[b];
  const int baseS = (blk & 511) * 4;
  if (baseS > len) return;         // block-uniform exit
  for (int c = tid; c < 2304; c += 256) w3[c] = ws[W3_OFF + c];
  __syncthreads();
  const int s = baseS + wave;
  if (s > len) return;             // e needed up to index len (stencil)
  const int row = b * SS + s;
  const float4* xr = (const float4*)(x + (size_t)row * DD);
  const float4* w0p = (const float4*)(w3);
  const float4* w1p = (const float4*)(w3 + DD);
  const float4* w2p = (const float4*)(w3 + 2 * DD);
  float a0 = 0.f, a1 = 0.f, a2 = 0.f;
#pragma unroll
  for (int q = 0; q < 3; ++q) {
    int f = lane + q * 64;         // float4 index, 192 per row
    float4 xv = xr[f];
    float4 w0 = w0p[f], w1 = w1p[f], w2 = w2p[f];
    a0 += w0.x * xv.x + w0.y * xv.y + w0.z * xv.z + w0.w * xv.w;
    a1 += w1.x * xv.x + w1.y * xv.y + w1.z * xv.z + w1.w * xv.w;
    a2 += w2.x * xv.x + w2.y * xv.y + w2.z * xv.z + w2.w * xv.w;
  }
#pragma unroll
  for (int m = 1; m < 64; m <<= 1) {
    a0 += __shfl_xor(a0, m);
    a1 += __shfl_xor(a1, m);
    a2 += __shfl_xor(a2, m);
  }
  if (lane == 0) { e0[row] = a0; e1[row] = a1; e2[row] = a2; }
}

// K3: fused alpha (stencil+sigmoid+mask) + per-batch prefix scan (wave shuffles,
// single barrier). aacc_t = P_t - floor(P_t); fire where floor increments.
__global__ __launch_bounds__(256) void k3_scan(
    const float* __restrict__ ws_ro, const int* __restrict__ lens,
    float2* __restrict__ wpk_g, int* __restrict__ ft_g,
    int* __restrict__ lenws, float* __restrict__ out_len) {
  __shared__ double wtot[4];
  const int b = blockIdx.x, tid = threadIdx.x;
  const int wave = tid >> 6, lane = tid & 63;
  const float* e0 = ws_ro + E0_OFF + b * SS;
  const float* e1 = ws_ro + E1_OFF + b * SS;
  const float* e2 = ws_ro + E2_OFF + b * SS;
  float2* wpk = wpk_g + b * SS;
  int* ft = ft_g + b * SS;
  const float bias = ws_ro[BIAS_OFF];
  const int len = lens[b];
  const int t0 = tid * 8;
  float a[8];
  double incl[8];
  double run = 0.0;
#pragma unroll
  for (int e = 0; e < 8; ++e) {
    int t = t0 + e;
    float av = 0.f;
    if (t < len) {
      float z = bias + e1[t];
      if (t > 0) z += e0[t - 1];
      if (t < SS - 1) z += e2[t + 1]; // SAME-pad: no x[s+1] term at s = S-1
      av = 1.f / (1.f + expf(-z));
    }
    a[e] = av;
    run += (double)av;
    incl[e] = run;
  }
  double v = run; // inclusive wave-scan of per-thread totals
#pragma unroll
  for (int m = 1; m < 64; m <<= 1) {
    double o = __shfl_up(v, m);
    if (lane >= m) v += o;
  }
  if (lane == 63) wtot[wave] = v;
  __syncthreads();
  double woff = 0.0;
  for (int w = 0; w < wave; ++w) woff += wtot[w];
  double excl = woff + v - run;
  double Pprev = excl;
  int Fprev = (int)floor(excl);
#pragma unroll
  for (int e = 0; e < 8; ++e) {
    int t = t0 + e;
    double P = excl + incl[e];
    int F = (int)floor(P);
    bool fire = (F > Fprev); // alpha in [0,1) => F steps by at most 1
    float2 wv;
    wv.x = fire ? (float)((double)F - Pprev) : a[e]; // a1 on fire, alpha otherwise
    wv.y = fire ? (float)(P - (double)F) : 0.f;      // a2 carried to next segment
    wpk[t] = wv;
    if (fire) ft[F - 1] = t;
    Pprev = P;
    Fprev = F;
  }
  if (tid == 255) {
    int L = (int)floor(woff + v);
    lenws[b] = L;
    out_len[b] = (float)L;
  }
}

// K4: one wave per output row j. Row j = wnext[ft[j-1]]*x[ft[j-1]]
//   + sum_{ft[j-1] < t < ft[j]} wcur[t]*x[t] + wcur[ft[j]]*x[ft[j]]. j>=L -> zeros.
// Nontemporal stores: out is write-once, keep L2/L3 for the x gather.
__global__ __launch_bounds__(256) void k4_emit(
    const float* __restrict__ x, const float* __restrict__ ws_ro,
    float* __restrict__ out) {
  const int tid = threadIdx.x, wave = tid >> 6, lane = tid & 63;
  const int row = blockIdx.x * 4 + wave; // b*SS + j
  const int b = row >> 11, j = row & (SS - 1);
  nfloat4* orow = (nfloat4*)(out + (size_t)row * DD);
  const int L = ((const int*)ws_ro)[LEN_OFF + b];
  if (j >= L) {
    nfloat4 z = {0.f, 0.f, 0.f, 0.f};
    __builtin_nontemporal_store(z, orow + lane);
    __builtin_nontemporal_store(z, orow + lane + 64);
    __builtin_nontemporal_store(z, orow + lane + 128);
    return;
  }
  const int* ft = ((const int*)ws_ro) + FT_OFF + b * SS;
  const float2* wpk = (const float2*)(ws_ro + WPK_OFF) + b * SS;
  int start = (j == 0) ? 0 : ft[j - 1];
  int end = ft[j];
  nfloat4 acc0 = {0, 0, 0, 0}, acc1 = {0, 0, 0, 0}, acc2 = {0, 0, 0, 0};
  for (int t = start; t <= end; ++t) {
    float2 wv = wpk[t];
    float w = (j > 0 && t == start) ? wv.y : wv.x;
    const nfloat4* xr = (const nfloat4*)(x + ((size_t)b * SS + t) * DD);
    nfloat4 v0 = xr[lane], v1 = xr[lane + 64], v2 = xr[lane + 128];
    acc0 += w * v0;
    acc1 += w * v1;
    acc2 += w * v2;
  }
  __builtin_nontemporal_store(acc0, orow + lane);
  __builtin_nontemporal_store(acc1, orow + lane + 64);
  __builtin_nontemporal_store(acc2, orow + lane + 128);
}

extern "C" void kernel_launch(void* const* d_in, const int* in_sizes, int n_in,
                              void* d_out, int out_size, void* d_ws, size_t ws_size,
                              hipStream_t stream) {
  const float* x      = (const float*)d_in[0]; // (B,S,D)
  const int*   lens   = (const int*)d_in[1];   // (B,)
  const float* conv_w = (const float*)d_in[2]; // (D,D,3)
  const float* conv_b = (const float*)d_in[3]; // (D,)
  const float* lin_w  = (const float*)d_in[4]; // (1,D)
  const float* lin_b  = (const float*)d_in[5]; // (1,)
  float* out = (float*)d_out;                  // B*S*D floats then B lens (as float)
  float* ws = (float*)d_ws;

  float* e0 = ws + E0_OFF;
  float* e1 = ws + E1_OFF;
  float* e2 = ws + E2_OFF;
  float2* wpk = (float2*)(ws + WPK_OFF);
  int* ft = (int*)(ws + FT_OFF);
  int* lenws = (int*)(ws + LEN_OFF);
  float* out_len = out + (size_t)NROW * DD;

  k1a_fold_part<<<NSLICE * 9, 256, 0, stream>>>(conv_w, lin_w, ws);
  k1r_fold_reduce<<<10, 256, 0, stream>>>(conv_b, lin_w, lin_b, ws);
  k2a_dots<<<NROW / 4, 256, 0, stream>>>(x, ws, lens, e0, e1, e2);
  k3_scan<<<BB, 256, 0, stream>>>(ws, lens, wpk, ft, lenws, out_len);
  k4_emit<<<NROW / 4, 256, 0, stream>>>(x, ws, out);
}